// Round 4
// baseline (158.536 us; speedup 1.0000x reference)
//
#include <hip/hip_runtime.h>
#include <hip/hip_bf16.h>
#include <math.h>

typedef unsigned short ushort_t;
typedef unsigned int uint_t;
typedef __bf16 bf16x8 __attribute__((ext_vector_type(8)));
typedef float f32x4 __attribute__((ext_vector_type(4)));

#define NSEQ 2048
#define BH   32        // B*H
// q pre-scale: HEAD_DIM^-0.5 * log2(e) so softmax runs in exp2 domain
#define QSCALE 0.3606737602222409f

__device__ __forceinline__ float exp2_fast(float x) {
#if __has_builtin(__builtin_amdgcn_exp2f)
    return __builtin_amdgcn_exp2f(x);
#else
    return exp2f(x);
#endif
}

union U8 { ushort_t u[8]; bf16x8 v; uint4 q; uint_t w[4]; };
union F8 { float f[8]; float4 v4[2]; };

// pack two floats -> bf16x2 (v_cvt_pk_bf16_f32 on gfx950)
__device__ __forceinline__ uint_t pk2(float a, float b) {
    __hip_bfloat162 h2 = __float22bfloat162_rn(make_float2(a, b));
    union { __hip_bfloat162 h; uint_t u; } cv; cv.h = h2; return cv.u;
}

// split 8 fp32 into bf16 hi + bf16 lo (residual), packed
__device__ __forceinline__ void split8(const F8& x, U8& hi, U8& lo) {
#pragma unroll
    for (int p = 0; p < 4; ++p) {
        const float a = x.f[2*p], b = x.f[2*p+1];
        const uint_t hw = pk2(a, b);
        hi.w[p] = hw;
        const float ha = __uint_as_float(hw << 16);
        const float hb = __uint_as_float(hw & 0xFFFF0000u);
        lo.w[p] = pk2(a - ha, b - hb);
    }
}

// ---------------------------------------------------------------------------
// Kernel 0: pack Wq/Wk into MFMA-B-fragment order, split bf16 hi/lo.
// wpk[mat][((ct*4+f)*64+lane)*8+j] = W[ct*16+(lane&15)][f*32+(lane>>4)*8+j]
// ---------------------------------------------------------------------------
__global__ __launch_bounds__(256) void wpack_kernel(
    const float* __restrict__ Wq, const float* __restrict__ Wk,
    ushort_t* __restrict__ wpk_hi, ushort_t* __restrict__ wpk_lo)
{
    const int idx  = blockIdx.x * 256 + threadIdx.x;   // 0..4095
    const int lane = idx & 63;
    const int f    = (idx >> 6) & 3;
    const int ct   = (idx >> 8) & 7;
    const int mat  = idx >> 11;
    const float* W = mat ? Wk : Wq;
    const float* src = W + (size_t)(ct * 16 + (lane & 15)) * 128
                         + f * 32 + (lane >> 4) * 8;
    F8 x; x.v4[0] = *(const float4*)src; x.v4[1] = *(const float4*)(src + 4);
    U8 hi, lo;
    split8(x, hi, lo);
    const size_t dst = (size_t)mat * 16384 + ((size_t)(ct * 4 + f) * 64 + lane) * 8;
    *(uint4*)(wpk_hi + dst) = hi.q;
    *(uint4*)(wpk_lo + dst) = lo.q;
}

// ---------------------------------------------------------------------------
// Kernel 1: Q/K projections on MFMA (split-bf16, XhWh+XlWh+XhWl),
// V projection + V^T store on VALU. 512 blocks x 256 threads; 16 rows/block.
// Waves 0,1 -> Q (head-tiles 0-3 / 4-7); waves 2,3 -> K.
// B-fragments reloaded per head-tile (unroll 1) to keep VGPRs low.
// ---------------------------------------------------------------------------
__global__ __launch_bounds__(256, 2) void proj_kernel(
    const float* __restrict__ query, const float* __restrict__ key,
    const float* __restrict__ value,
    const float* __restrict__ bq, const float* __restrict__ bk,
    const float* __restrict__ Wv, const float* __restrict__ bv,
    const ushort_t* __restrict__ wpk_hi, const ushort_t* __restrict__ wpk_lo,
    ushort_t* __restrict__ q_hi, ushort_t* __restrict__ q_lo,
    ushort_t* __restrict__ k_hi, ushort_t* __restrict__ k_lo,
    ushort_t* __restrict__ vt)
{
    const int t   = threadIdx.x;
    const int w   = t >> 6;
    const int l   = t & 63;
    const int n16 = l & 15;
    const int g   = l >> 4;
    const int rbase = blockIdx.x * 16;
    const int b = rbase >> 11;

    const int isK    = w >> 1;
    const int cthalf = (w & 1) * 4;

    // A fragments: X rows rbase+n16, k = f*32 + g*8 + j, fp32 -> hi/lo
    const float* X = isK ? key : query;
    const float* xrow = X + (size_t)(rbase + n16) * 128 + g * 8;
    bf16x8 ah[4], al[4];
#pragma unroll
    for (int f = 0; f < 4; ++f) {
        F8 x;
        x.v4[0] = *(const float4*)(xrow + f * 32);
        x.v4[1] = *(const float4*)(xrow + f * 32 + 4);
        U8 hi, lo;
        split8(x, hi, lo);
        ah[f] = hi.v; al[f] = lo.v;
    }

    const float* bias = isK ? bk : bq;
    ushort_t* dhi = isK ? k_hi : q_hi;
    ushort_t* dlo = isK ? k_lo : q_lo;
    const float scale = isK ? 1.0f : QSCALE;
    const int nbase = (rbase & 2047) + g * 4;

#pragma unroll 1
    for (int ctl = 0; ctl < 4; ++ctl) {
        const int h = cthalf + ctl;
        // B fragments for this head-tile (coalesced 16B/lane, L2-resident)
        bf16x8 bhf[4], blf[4];
#pragma unroll
        for (int f = 0; f < 4; ++f) {
            const size_t o = (size_t)isK * 16384
                           + ((size_t)(h * 4 + f) * 64 + l) * 8;
            bhf[f] = *(const bf16x8*)(wpk_hi + o);
            blf[f] = *(const bf16x8*)(wpk_lo + o);
        }
        const float bval = bias[h * 16 + n16];
        f32x4 acc = {bval, bval, bval, bval};
#pragma unroll
        for (int f = 0; f < 4; ++f) {
            acc = __builtin_amdgcn_mfma_f32_16x16x32_bf16(ah[f], bhf[f], acc, 0, 0, 0);
            acc = __builtin_amdgcn_mfma_f32_16x16x32_bf16(al[f], bhf[f], acc, 0, 0, 0);
            acc = __builtin_amdgcn_mfma_f32_16x16x32_bf16(ah[f], blf[f], acc, 0, 0, 0);
        }
        const size_t abase = ((size_t)(b * 8 + h) * NSEQ + nbase) * 16 + n16;
        const float a0 = acc[0]*scale, a1 = acc[1]*scale;
        const float a2 = acc[2]*scale, a3 = acc[3]*scale;
        const uint_t h01 = pk2(a0, a1), h23 = pk2(a2, a3);
        const uint_t l01 = pk2(a0 - __uint_as_float(h01 << 16),
                               a1 - __uint_as_float(h01 & 0xFFFF0000u));
        const uint_t l23 = pk2(a2 - __uint_as_float(h23 << 16),
                               a3 - __uint_as_float(h23 & 0xFFFF0000u));
        dhi[abase]      = (ushort_t)h01;
        dhi[abase + 16] = (ushort_t)(h01 >> 16);
        dhi[abase + 32] = (ushort_t)h23;
        dhi[abase + 48] = (ushort_t)(h23 >> 16);
        dlo[abase]      = (ushort_t)l01;
        dlo[abase + 16] = (ushort_t)(l01 >> 16);
        dlo[abase + 32] = (ushort_t)l23;
        dlo[abase + 48] = (ushort_t)(l23 >> 16);
    }

    // V projection (VALU, K=16) + vt transpose store
    const int e  = t & 127;
    const int rh = t >> 7;
    const int r0 = rbase + rh * 8;
    const float4* Wv4 = (const float4*)(Wv + (size_t)e * 16);
    const float4 wv0 = Wv4[0], wv1 = Wv4[1], wv2 = Wv4[2], wv3 = Wv4[3];
    const float bvv = bv[e];
    F8 af;
#pragma unroll
    for (int r = 0; r < 8; ++r) {
        const float4* xv4 = (const float4*)(value + (size_t)(r0 + r) * 16);
        const float4 x0 = xv4[0], x1 = xv4[1], x2 = xv4[2], x3 = xv4[3];
        float a = bvv;
        a += wv0.x*x0.x + wv0.y*x0.y + wv0.z*x0.z + wv0.w*x0.w;
        a += wv1.x*x1.x + wv1.y*x1.y + wv1.z*x1.z + wv1.w*x1.w;
        a += wv2.x*x2.x + wv2.y*x2.y + wv2.z*x2.z + wv2.w*x2.w;
        a += wv3.x*x3.x + wv3.y*x3.y + wv3.z*x3.z + wv3.w*x3.w;
        af.f[r] = a;
    }
    U8 vpk;
#pragma unroll
    for (int p = 0; p < 4; ++p) vpk.w[p] = pk2(af.f[2*p], af.f[2*p+1]);
    const int hv = e >> 4, dd = e & 15;
    *(uint4*)(vt + ((size_t)(b * 8 + hv) * 16 + dd) * NSEQ + (r0 & 2047)) = vpk.q;
}

// ---------------------------------------------------------------------------
// Kernel 2a: exact row-max pass. 1 MFMA / 16 keys (hi-score approx, err<~0.5
// vs full split score -- harmless: only shifts exp2 args, overflow headroom
// is 2^127). Per-lane running max, single cross-lane reduce at the end.
// ---------------------------------------------------------------------------
__global__ __launch_bounds__(256, 2) void maxk_kernel(
    const ushort_t* __restrict__ q_hi,
    const ushort_t* __restrict__ k_hi, const ushort_t* __restrict__ k_lo,
    float* __restrict__ m_arr)
{
    const int t    = threadIdx.x;
    const int wave = t >> 6;
    const int l    = t & 63;
    const int col  = l & 15;
    const int g    = l >> 4;

    const int bh = blockIdx.y;
    const int qb = blockIdx.x * 64 + wave * 16;

    const size_t qoff = ((size_t)(bh * NSEQ + qb + col)) * 16 + (g & 1) * 8;
    const bf16x8 bq1 = *(const bf16x8*)(q_hi + qoff);

    const ushort_t* ksel = (g < 2) ? k_hi : k_lo;
    const ushort_t* aptr = ksel + ((size_t)(bh * NSEQ + col)) * 16 + (g & 1) * 8;

    float mrun = -INFINITY;
    const f32x4 z = {0.f, 0.f, 0.f, 0.f};
#pragma unroll 2
    for (int kb = 0; kb < 64; ++kb) {
        const bf16x8 a1 = *(const bf16x8*)(aptr + (size_t)kb * 512);
        const bf16x8 a2 = *(const bf16x8*)(aptr + (size_t)kb * 512 + 256);
        const f32x4 st1 = __builtin_amdgcn_mfma_f32_16x16x32_bf16(a1, bq1, z, 0, 0, 0);
        const f32x4 st2 = __builtin_amdgcn_mfma_f32_16x16x32_bf16(a2, bq1, z, 0, 0, 0);
        mrun = fmaxf(mrun, fmaxf(fmaxf(st1[0], st1[1]), fmaxf(st1[2], st1[3])));
        mrun = fmaxf(mrun, fmaxf(fmaxf(st2[0], st2[1]), fmaxf(st2[2], st2[3])));
    }
    mrun = fmaxf(mrun, __shfl_xor(mrun, 16));
    mrun = fmaxf(mrun, __shfl_xor(mrun, 32));
    if (l < 16) m_arr[bh * NSEQ + qb + col] = mrun;
}

// ---------------------------------------------------------------------------
// Kernel 2b: flash attention, rescale-free (uses precomputed row max).
// The (s - m) subtraction is folded into the MFMA C-initializer (-m).
// o/lacc are pure MFMA accumulators -- never touched by VALU in the loop.
// ---------------------------------------------------------------------------
__global__ __launch_bounds__(256, 2) void attn_kernel(
    const ushort_t* __restrict__ q_hi, const ushort_t* __restrict__ q_lo,
    const ushort_t* __restrict__ k_hi, const ushort_t* __restrict__ k_lo,
    const ushort_t* __restrict__ vt, const float* __restrict__ m_arr,
    float* __restrict__ ctx)
{
    const int t    = threadIdx.x;
    const int wave = t >> 6;
    const int l    = t & 63;
    const int col  = l & 15;
    const int g    = l >> 4;

    const int bh = blockIdx.y;
    const int qb = blockIdx.x * 64 + wave * 16;

    __shared__ __align__(16) ushort_t lds_p[4][16 * 40];
    ushort_t* pbuf = lds_p[wave];

    U8 Uz, Uo;
#pragma unroll
    for (int i = 0; i < 8; ++i) { Uz.u[i] = 0; Uo.u[i] = 0x3F80; }
    const bf16x8 zf = Uz.v, ones = Uo.v;

    const size_t qoff = ((size_t)(bh * NSEQ + qb + col)) * 16 + (g & 1) * 8;
    const bf16x8 bq1 = *(const bf16x8*)(q_hi + qoff);
    bf16x8 bq2 = *(const bf16x8*)(q_lo + qoff);
    bq2 = (g < 2) ? bq2 : zf;

    const float mcol = m_arr[bh * NSEQ + qb + col];
    const f32x4 zin = {-mcol, -mcol, -mcol, -mcol};

    const ushort_t* ksel = (g < 2) ? k_hi : k_lo;
    const ushort_t* aptr = ksel + ((size_t)(bh * NSEQ + col)) * 16 + (g & 1) * 8;
    const ushort_t* vptr = vt + ((size_t)(bh * 16 + col)) * NSEQ + g * 8;

    f32x4 o    = {0.f, 0.f, 0.f, 0.f};
    f32x4 lacc = {0.f, 0.f, 0.f, 0.f};

    bf16x8 a1 = *(const bf16x8*)(aptr);
    bf16x8 a2 = *(const bf16x8*)(aptr + 256);
    bf16x8 av = *(const bf16x8*)(vptr);

    for (int kb = 0; kb < 64; ++kb) {
        const int kn = (kb + 1) & 63;
        bf16x8 na1 = *(const bf16x8*)(aptr + (size_t)kn * 512);
        bf16x8 na2 = *(const bf16x8*)(aptr + (size_t)kn * 512 + 256);
        bf16x8 nav = *(const bf16x8*)(vptr + (size_t)kn * 32);

        // S^T - m  (C init carries the -m)
        f32x4 st1 = __builtin_amdgcn_mfma_f32_16x16x32_bf16(a1, bq2, zin, 0, 0, 0);
        st1       = __builtin_amdgcn_mfma_f32_16x16x32_bf16(a1, bq1, st1, 0, 0, 0);
        f32x4 st2 = __builtin_amdgcn_mfma_f32_16x16x32_bf16(a2, bq2, zin, 0, 0, 0);
        st2       = __builtin_amdgcn_mfma_f32_16x16x32_bf16(a2, bq1, st2, 0, 0, 0);

        const float p0 = exp2_fast(st1[0]);
        const float p1 = exp2_fast(st1[1]);
        const float p2 = exp2_fast(st1[2]);
        const float p3 = exp2_fast(st1[3]);
        const float p4 = exp2_fast(st2[0]);
        const float p5 = exp2_fast(st2[1]);
        const float p6 = exp2_fast(st2[2]);
        const float p7 = exp2_fast(st2[3]);

        uint2 w1; w1.x = pk2(p0, p1); w1.y = pk2(p2, p3);
        uint2 w2; w2.x = pk2(p4, p5); w2.y = pk2(p6, p7);
        *(uint2*)(pbuf + col * 40 + 4 * g)      = w1;
        *(uint2*)(pbuf + col * 40 + 16 + 4 * g) = w2;
        const bf16x8 bp = *(const bf16x8*)(pbuf + col * 40 + 8 * g);

        o    = __builtin_amdgcn_mfma_f32_16x16x32_bf16(av,   bp, o,    0, 0, 0);
        lacc = __builtin_amdgcn_mfma_f32_16x16x32_bf16(ones, bp, lacc, 0, 0, 0);

        a1 = na1; a2 = na2; av = nav;
    }

    const float linv = 1.0f / lacc[0];
    f32x4 res;
    res[0] = o[0] * linv; res[1] = o[1] * linv;
    res[2] = o[2] * linv; res[3] = o[3] * linv;
    *(f32x4*)(ctx + ((size_t)(bh * NSEQ + qb + col)) * 16 + 4 * g) = res;
}

// ---------------------------------------------------------------------------
// Kernel 3: output projection (fp32). Unchanged.
// ---------------------------------------------------------------------------
__global__ __launch_bounds__(256) void outproj_kernel(
    const float* __restrict__ ctxws, const float* __restrict__ Wo,
    const float* __restrict__ bo, float* __restrict__ out)
{
    __shared__ float wo_s[16 * 132];
    const int t = threadIdx.x;
    for (int i = t; i < 2048; i += 256) {
        const int j = i >> 7, e2 = i & 127;
        wo_s[j * 132 + e2] = Wo[i];
    }
    __syncthreads();

    const int rl = t >> 4, j = t & 15;
    const int row = blockIdx.x * 16 + rl;
    const int b = row >> 11, n = row & 2047;
    float acc = bo[j];
#pragma unroll
    for (int h = 0; h < 8; ++h) {
        const float4* cp4 = (const float4*)(ctxws + (((size_t)(b*8 + h) * NSEQ) + n) * 16);
#pragma unroll
        for (int d4 = 0; d4 < 4; ++d4) {
            const float4 cc = cp4[d4];
            const float* wp = &wo_s[j * 132 + h * 16 + d4 * 4];
            acc += cc.x*wp[0] + cc.y*wp[1] + cc.z*wp[2] + cc.w*wp[3];
        }
    }
    out[(size_t)row * 16 + j] = acc;
}

// ---------------------------------------------------------------------------
extern "C" void kernel_launch(void* const* d_in, const int* in_sizes, int n_in,
                              void* d_out, int out_size, void* d_ws, size_t ws_size,
                              hipStream_t stream)
{
    const float* query = (const float*)d_in[0];
    const float* key_  = (const float*)d_in[1];
    const float* value = (const float*)d_in[2];
    const float* Wq = (const float*)d_in[3];
    const float* bq = (const float*)d_in[4];
    const float* Wk = (const float*)d_in[5];
    const float* bk = (const float*)d_in[6];
    const float* Wv = (const float*)d_in[7];
    const float* bv = (const float*)d_in[8];
    const float* Wo = (const float*)d_in[9];
    const float* bo = (const float*)d_in[10];
    float* out = (float*)d_out;

    // ws: 5 bf16 arrays (2MB) + ctx fp32 (4MB) + packed W (128KB) + m (256KB)
    ushort_t* q_hi = (ushort_t*)d_ws;
    ushort_t* q_lo = q_hi + (1u << 20);
    ushort_t* k_hi = q_hi + (2u << 20);
    ushort_t* k_lo = q_hi + (3u << 20);
    ushort_t* vt   = q_hi + (4u << 20);
    float*    ctx  = (float*)((char*)d_ws + (10u << 20));
    ushort_t* wpk_hi = (ushort_t*)((char*)d_ws + (14u << 20));
    ushort_t* wpk_lo = wpk_hi + 32768;
    float*    m_arr  = (float*)((char*)d_ws + (14u << 20) + (1u << 18));

    wpack_kernel<<<dim3(16), dim3(256), 0, stream>>>(Wq, Wk, wpk_hi, wpk_lo);
    proj_kernel<<<dim3(512), dim3(256), 0, stream>>>(
        query, key_, value, bq, bk, Wv, bv, wpk_hi, wpk_lo,
        q_hi, q_lo, k_hi, k_lo, vt);
    maxk_kernel<<<dim3(32, 32), dim3(256), 0, stream>>>(q_hi, k_hi, k_lo, m_arr);
    attn_kernel<<<dim3(32, 32), dim3(256), 0, stream>>>(
        q_hi, q_lo, k_hi, k_lo, vt, m_arr, ctx);
    outproj_kernel<<<dim3(512), dim3(256), 0, stream>>>(ctx, Wo, bo, out);
}